// Round 6
// baseline (125.636 us; speedup 1.0000x reference)
//
#include <hip/hip_runtime.h>
#include <hip/hip_bf16.h>
#include <cstdint>
#include <cstddef>

// PointAttention: out = concat( diag_softmax(eps_mlp((q_i - k_j + pij)*s)) * v , features )
// Folding: AE=s*A2@E1, BE=s*B2@E1, G=s*D2@E1, c0=s*(ab2-bb2+db2)@E1+eb1 (folded into qe); eb2 drops out.
// Softmax: logits O(1) -> no max-sub; E2 panel pre-scaled by log2e -> exp2.
// k_main: 2x2 wave-tiling (each ds_read_b128 feeds 2 MFMAs), dbuf HD/HE panels (2 barriers/chunk),
//         full voxel per block. ~240 VGPR -> launch_bounds(256,2). (256,4) spilled badly (r3); (256,3)
//         was the 1x4-tile regime (r4/r5, 104us LDS-bound).

#define SCALE 0.08838834764831843f
#define LOG2E 1.4426950408889634f

typedef __bf16 bf16x8 __attribute__((ext_vector_type(8)));
typedef float f32x16 __attribute__((ext_vector_type(16)));

__device__ __forceinline__ ushort f2b(float f){
  __hip_bfloat16 h = __float2bfloat16(f);
  return __builtin_bit_cast(ushort, h);
}
__device__ __forceinline__ float b2f(uint32_t s){
  union { uint32_t u; float f; } x; x.u = s << 16; return x.f;
}
__device__ __forceinline__ float blo(uint32_t u){
  union { uint32_t x; float f; } v; v.x = u << 16; return v.f;
}
__device__ __forceinline__ float bhi(uint32_t u){
  union { uint32_t x; float f; } v; v.x = u & 0xffff0000u; return v.f;
}
__device__ __forceinline__ uint32_t pk2(float a, float b){
  union { __hip_bfloat162 h2; uint32_t u; } x;
  x.h2.x = __float2bfloat16(a); x.h2.y = __float2bfloat16(b);
  return x.u;
}
__device__ __forceinline__ f32x16 MFMA(uint4 a, uint4 b, f32x16 c){
  return __builtin_amdgcn_mfma_f32_32x32x16_bf16(
      __builtin_bit_cast(bf16x8, a), __builtin_bit_cast(bf16x8, b), c, 0, 0, 0);
}

// ---------------- Kernel P: weight folding + panelization ----------------
// panel[k_oct][x][e] = Mat[8*k_oct+e][x]  (bf16, conflict-free for frag ds_read_b128)
__global__ __launch_bounds__(256) void k_pre(
    const float* __restrict__ A2, const float* __restrict__ B2, const float* __restrict__ D2,
    const float* __restrict__ E1, const float* __restrict__ E2,
    const float* __restrict__ O1, const float* __restrict__ O2,
    const float* __restrict__ ab2, const float* __restrict__ bb2, const float* __restrict__ db2,
    const float* __restrict__ eb1,
    const float* __restrict__ D1, const float* __restrict__ db1,
    ushort* __restrict__ aep, ushort* __restrict__ bep, ushort* __restrict__ gtp,
    ushort* __restrict__ e2p, ushort* __restrict__ o2p, ushort* __restrict__ o1t,
    ushort* __restrict__ d1p, float* __restrict__ c0)
{
  const int bid = blockIdx.x, tid = threadIdx.x;
  if (bid < 192){                 // AE / BE / G = s*(W @ E1), panelized
    const float* W = (bid < 64) ? A2 : (bid < 128) ? B2 : D2;
    ushort* dst    = (bid < 64) ? aep : (bid < 128) ? bep : gtp;
    int flat = (bid & 63)*256 + tid;
    int co = flat >> 10, rem = flat & 1023, h = rem >> 3, i = rem & 7;
    int r = co*8 + i;
    float acc = 0.f;
    for (int t = 0; t < 128; ++t) acc = fmaf(W[r*128 + t], E1[t*128 + h], acc);
    dst[(co*128 + h)*8 + i] = f2b(acc * SCALE);
  } else if (bid < 256){          // E2 panel, pre-scaled by log2e (softmax via exp2)
    int flat = (bid - 192)*256 + tid;
    int co = flat >> 10, rem = flat & 1023, d = rem >> 3, i = rem & 7;
    e2p[(co*128 + d)*8 + i] = f2b(E2[(co*8 + i)*128 + d] * LOG2E);
  } else if (bid < 320){          // O2 panel
    int flat = (bid - 256)*256 + tid;
    int co = flat >> 10, rem = flat & 1023, d = rem >> 3, i = rem & 7;
    o2p[(co*128 + d)*8 + i] = f2b(O2[(co*8 + i)*128 + d]);
  } else if (bid < 352){          // O1^T panel (A-operand: rows=o, k=f)
    int flat = (bid - 320)*256 + tid;   // 8192 elems
    int fo = flat >> 10, rem = flat & 1023, o = rem >> 3, e = rem & 7;
    o1t[(fo*128 + o)*8 + e] = f2b(O1[(fo*8 + e)*128 + o]);
  } else if (bid < 360){          // D1 A-frag panel: [2 koct][128 cd][8]
    int flat = (bid - 352)*256 + tid;   // 2048 elems
    int koct = flat >> 10, cd = (flat >> 3) & 127, e = flat & 7;
    float val = 0.f;
    if (koct == 0){
      if (e < 3) val = D1[e*128 + cd];
      else if (e == 3) val = db1[cd];
    }
    d1p[flat] = f2b(val);
  } else {
    if (tid < 128){
      float acc = 0.f;
      for (int t = 0; t < 128; ++t) acc = fmaf(ab2[t] - bb2[t] + db2[t], E1[t*128 + tid], acc);
      c0[tid] = acc * SCALE + eb1[tid];
    }
  }
}

// ---------------- Kernel Q: per-point qe/ke/v + features passthrough ----------------
__device__ __forceinline__ void gemm64x128(const ushort (*sa)[64][8], const ushort (*sw)[128][8],
                                           int w, int l31, int hl, int p0,
                                           const float* __restrict__ bias,
                                           ushort* __restrict__ dst)
{
  const int rw = w >> 1, ctb = (w & 1) * 2;
  f32x16 acc0, acc1;
#pragma unroll
  for (int r = 0; r < 16; ++r){ acc0[r] = 0.f; acc1[r] = 0.f; }
#pragma unroll
  for (int kk = 0; kk < 8; ++kk){
    uint4 a  = *(const uint4*)&sa[2*kk + hl][32*rw + l31][0];
    uint4 b0 = *(const uint4*)&sw[2*kk + hl][32*ctb + l31][0];
    uint4 b1 = *(const uint4*)&sw[2*kk + hl][32*(ctb+1) + l31][0];
    acc0 = MFMA(a, b0, acc0);
    acc1 = MFMA(a, b1, acc1);
  }
#pragma unroll
  for (int t = 0; t < 2; ++t){
    const f32x16 acc = t ? acc1 : acc0;
    const int d = 32*(ctb + t) + l31;
    const float bv = bias ? bias[d] : 0.f;
#pragma unroll
    for (int r = 0; r < 16; ++r){
      int row = 32*rw + (r & 3) + 8*(r >> 2) + 4*hl;
      dst[(size_t)(p0 + row)*128 + d] = f2b(acc[r] + bv);
    }
  }
}

__global__ __launch_bounds__(256, 2) void k_point(
    const float* __restrict__ pv, const float* __restrict__ feat,
    const float* __restrict__ A1, const float* __restrict__ ab1,
    const float* __restrict__ B1, const float* __restrict__ bb1,
    const float* __restrict__ ob1, const float* __restrict__ ob2,
    const float* __restrict__ c0,
    const uint4* __restrict__ aep, const uint4* __restrict__ bep,
    const uint4* __restrict__ o1t, const uint4* __restrict__ o2p,
    ushort* __restrict__ qe_ws, ushort* __restrict__ ke_ws, ushort* __restrict__ v_ws,
    float* __restrict__ out)
{
  __shared__ ushort sW[16][128][8];   // 32 KB weight panel
  __shared__ ushort sA[16][64][8];    // 16 KB activation panel
  __shared__ ushort sF[8][64][8];     // 8 KB  feature panel
  __shared__ float  sLw[3][128];
  __shared__ float  sLb[128];
  __shared__ float  sLb2[128];

  const int tid = threadIdx.x;
  const int p0  = blockIdx.x * 64;
  const int w = tid >> 6, lane = tid & 63, l31 = lane & 31, hl = lane >> 5;

  // exact f32 features passthrough: out[:,:,128:192]
  for (int idx = tid; idx < 64*16; idx += 256){
    int p = idx >> 4, k4 = idx & 15;
    float4 f = ((const float4*)(feat + (size_t)(p0 + p)*64))[k4];
    ((float4*)(out + (size_t)(p0 + p)*192 + 128))[k4] = f;
  }

  // ---- phase A: ha = relu(xyz@A1+ab1); qe = ha@AE + c0 ----
  for (int idx = tid; idx < 2048; idx += 256) ((uint4*)sW)[idx] = aep[idx];
  for (int idx = tid; idx < 384; idx += 256) ((float*)sLw)[idx] = A1[idx];
  if (tid < 128) sLb[tid] = ab1[tid];
  __syncthreads();
  {
    int p = tid & 63, ob = tid >> 6;
    float x0 = pv[(size_t)(p0+p)*3+0], x1 = pv[(size_t)(p0+p)*3+1], x2 = pv[(size_t)(p0+p)*3+2];
#pragma unroll
    for (int it = 0; it < 4; ++it){
      int oct = ob + 4*it;
      float h[8];
#pragma unroll
      for (int e = 0; e < 8; ++e){
        int cd = oct*8 + e;
        float t = fmaf(x0, sLw[0][cd], fmaf(x1, sLw[1][cd], fmaf(x2, sLw[2][cd], sLb[cd])));
        h[e] = fmaxf(t, 0.f);
      }
      uint4 u; u.x = pk2(h[0],h[1]); u.y = pk2(h[2],h[3]); u.z = pk2(h[4],h[5]); u.w = pk2(h[6],h[7]);
      *(uint4*)&sA[oct][p][0] = u;
    }
  }
  __syncthreads();
  gemm64x128(sA, sW, w, l31, hl, p0, c0, qe_ws);
  __syncthreads();

  // ---- phase B: ke = hb@BE ----
  for (int idx = tid; idx < 2048; idx += 256) ((uint4*)sW)[idx] = bep[idx];
  for (int idx = tid; idx < 384; idx += 256) ((float*)sLw)[idx] = B1[idx];
  if (tid < 128) sLb[tid] = bb1[tid];
  __syncthreads();
  {
    int p = tid & 63, ob = tid >> 6;
    float x0 = pv[(size_t)(p0+p)*3+0], x1 = pv[(size_t)(p0+p)*3+1], x2 = pv[(size_t)(p0+p)*3+2];
#pragma unroll
    for (int it = 0; it < 4; ++it){
      int oct = ob + 4*it;
      float h[8];
#pragma unroll
      for (int e = 0; e < 8; ++e){
        int cd = oct*8 + e;
        float t = fmaf(x0, sLw[0][cd], fmaf(x1, sLw[1][cd], fmaf(x2, sLw[2][cd], sLb[cd])));
        h[e] = fmaxf(t, 0.f);
      }
      uint4 u; u.x = pk2(h[0],h[1]); u.y = pk2(h[2],h[3]); u.z = pk2(h[4],h[5]); u.w = pk2(h[6],h[7]);
      *(uint4*)&sA[oct][p][0] = u;
    }
  }
  __syncthreads();
  gemm64x128(sA, sW, w, l31, hl, p0, nullptr, ke_ws);
  __syncthreads();

  // ---- phase C: ho^T = relu(O1^T @ feat^T + ob1) ----
  for (int idx = tid; idx < 512; idx += 256){
    int p = idx & 63, fo = idx >> 6;
    const float* fp = feat + (size_t)(p0 + p)*64 + 8*fo;
    float4 f0 = ((const float4*)fp)[0], f1 = ((const float4*)fp)[1];
    uint4 u; u.x = pk2(f0.x,f0.y); u.y = pk2(f0.z,f0.w); u.z = pk2(f1.x,f1.y); u.w = pk2(f1.z,f1.w);
    *(uint4*)&sF[fo][p][0] = u;
  }
  for (int idx = tid; idx < 1024; idx += 256) ((uint4*)sW)[idx] = o1t[idx];
  if (tid < 128) sLb[tid] = ob1[tid];
  __syncthreads();
  {
    f32x16 acc0, acc1;
#pragma unroll
    for (int r = 0; r < 16; ++r){ acc0[r] = 0.f; acc1[r] = 0.f; }
#pragma unroll
    for (int kk = 0; kk < 4; ++kk){
      uint4 a  = *(const uint4*)&sW[2*kk + hl][32*w + l31][0];
      uint4 b0 = *(const uint4*)&sF[2*kk + hl][l31][0];
      uint4 b1 = *(const uint4*)&sF[2*kk + hl][32 + l31][0];
      acc0 = MFMA(a, b0, acc0);
      acc1 = MFMA(a, b1, acc1);
    }
#pragma unroll
    for (int t = 0; t < 2; ++t){
      const f32x16 acc = t ? acc1 : acc0;
      const int pt = 32*t + l31;
#pragma unroll
      for (int q = 0; q < 4; ++q){
        int o0 = 32*w + 8*q + 4*hl;
        float z0 = fmaxf(acc[4*q+0] + sLb[o0+0], 0.f);
        float z1 = fmaxf(acc[4*q+1] + sLb[o0+1], 0.f);
        float z2 = fmaxf(acc[4*q+2] + sLb[o0+2], 0.f);
        float z3 = fmaxf(acc[4*q+3] + sLb[o0+3], 0.f);
        uint2 u; u.x = pk2(z0, z1); u.y = pk2(z2, z3);
        *(uint2*)&sA[4*w + q][pt][4*hl] = u;
      }
    }
  }
  __syncthreads();

  // ---- phase D: v = ho @ O2 + ob2 ----
  for (int idx = tid; idx < 2048; idx += 256) ((uint4*)sW)[idx] = o2p[idx];
  if (tid < 128) sLb2[tid] = ob2[tid];
  __syncthreads();
  {
    const int rw = w >> 1, ctb = (w & 1) * 2;
    f32x16 acc0, acc1;
#pragma unroll
    for (int r = 0; r < 16; ++r){ acc0[r] = 0.f; acc1[r] = 0.f; }
#pragma unroll
    for (int kk = 0; kk < 8; ++kk){
      uint4 a  = *(const uint4*)&sA[2*kk + hl][32*rw + l31][0];
      uint4 b0 = *(const uint4*)&sW[2*kk + hl][32*ctb + l31][0];
      uint4 b1 = *(const uint4*)&sW[2*kk + hl][32*(ctb+1) + l31][0];
      acc0 = MFMA(a, b0, acc0);
      acc1 = MFMA(a, b1, acc1);
    }
#pragma unroll
    for (int t = 0; t < 2; ++t){
      const f32x16 acc = t ? acc1 : acc0;
      const int d = 32*(ctb + t) + l31;
      const float bias = sLb2[d];
#pragma unroll
      for (int r = 0; r < 16; ++r){
        int row = 32*rw + (r & 3) + 8*(r >> 2) + 4*hl;
        v_ws[(size_t)(p0 + row)*128 + d] = f2b(acc[r] + bias);
      }
    }
  }
}

// ---------------- Kernel M: per-voxel attention core (one voxel per block) ----------------
// 2x2 wave tiling: wave (wm,wn) = (w>>1, w&1).
// GEMM1: HE^T[h][p]; wave covers h-blocks {2wm,2wm+1}, p(ct)-blocks {2wn,2wn+1}.
// GEMM2: W[p][d];    wave covers p(rt)-blocks {2wm,2wm+1}, d-blocks {2wn,2wn+1}.
__global__ __launch_bounds__(256, 2) void k_main(
    const float* __restrict__ pv,
    const ushort* __restrict__ qe_ws, const ushort* __restrict__ ke_ws, const ushort* __restrict__ v_ws,
    const uint4* __restrict__ gtp, const uint4* __restrict__ e2p, const uint4* __restrict__ d1p,
    float* __restrict__ out)
{
  __shared__ ushort pA[16][128][8];   // 32 KB: HD panel
  __shared__ ushort pB[16][128][8];   // 32 KB: HE panel
  __shared__ ushort sQE[32][128];     // 8 KB: qe (+c0) bf16
  __shared__ float  sXYZ[32][3];      // 384 B

  const int tid = threadIdx.x;
  const int b   = blockIdx.x;
  const int w = tid >> 6, lane = tid & 63, l31 = lane & 31, hl = lane >> 5;
  const int wm = w >> 1, wn = w & 1;

  for (int idx = tid; idx < 96; idx += 256) ((float*)sXYZ)[idx] = pv[(size_t)b*96 + idx];
  for (int idx = tid; idx < 512; idx += 256)
    ((uint4*)sQE)[idx] = ((const uint4*)(qe_ws + (size_t)b*32*128))[idx];

  // ke fragments (j=l31, h = 64wm+32a+4hl+8q), bf16-packed
  uint2 kp[2][4];
#pragma unroll
  for (int a = 0; a < 2; ++a)
#pragma unroll
    for (int q = 0; q < 4; ++q)
      kp[a][q] = *(const uint2*)(ke_ws + (size_t)(b*32 + l31)*128 + 64*wm + 32*a + 4*hl + 8*q);

  uint4 wG[2][8], wE[2][8];
#pragma unroll
  for (int kk = 0; kk < 8; ++kk){
#pragma unroll
    for (int a = 0; a < 2; ++a){
      wG[a][kk] = gtp[(2*kk + hl)*128 + 64*wm + 32*a + l31];  // A rows h
      wE[a][kk] = e2p[(2*kk + hl)*128 + 64*wn + 32*a + l31];  // B cols d (log2e-scaled)
    }
  }
  uint4 wD = d1p[hl*128 + 32*w + l31];
  __syncthreads();

  const float xj0 = sXYZ[l31][0], xj1 = sXYZ[l31][1], xj2 = sXYZ[l31][2];

  auto hdgen = [&](int cn){
    f32x16 Z;
#pragma unroll
    for (int r = 0; r < 16; ++r) Z[r] = 0.f;
#pragma unroll
    for (int ct = 0; ct < 4; ++ct){
      const int i = 4*cn + ct;
      float dx = fabsf(sXYZ[i][0] - xj0);
      float dy = fabsf(sXYZ[i][1] - xj1);
      float dz = fabsf(sXYZ[i][2] - xj2);
      uint4 bD; bD.x = pk2(dx, dy); bD.y = pk2(dz, 1.0f); bD.z = 0u; bD.w = 0u;
      f32x16 t = MFMA(wD, bD, Z);
#pragma unroll
      for (int q = 0; q < 4; ++q){
        uint2 o;
        o.x = pk2(fmaxf(t[4*q+0],0.f), fmaxf(t[4*q+1],0.f));
        o.y = pk2(fmaxf(t[4*q+2],0.f), fmaxf(t[4*q+3],0.f));
        *(uint2*)&pA[4*w + q][32*ct + l31][4*hl] = o;
      }
    }
  };

  hdgen(0);
  __syncthreads();

  for (int cc = 0; cc < 8; ++cc){
    f32x16 acc[2][2];

    // ---- GEMM1 C-in: qe[i=4cc+2wn+bb][h] - ke[j=l31][h] ----
#pragma unroll
    for (int a = 0; a < 2; ++a){
#pragma unroll
      for (int q = 0; q < 4; ++q){
        float k0 = blo(kp[a][q].x), k1 = bhi(kp[a][q].x);
        float k2 = blo(kp[a][q].y), k3 = bhi(kp[a][q].y);
#pragma unroll
        for (int bb = 0; bb < 2; ++bb){
          uint2 qu = *(const uint2*)&sQE[4*cc + 2*wn + bb][64*wm + 32*a + 4*hl + 8*q];
          acc[a][bb][4*q+0] = blo(qu.x) - k0;
          acc[a][bb][4*q+1] = bhi(qu.x) - k1;
          acc[a][bb][4*q+2] = blo(qu.y) - k2;
          acc[a][bb][4*q+3] = bhi(qu.y) - k3;
        }
      }
    }
    // ---- GEMM1: each B-read feeds 2 MFMAs ----
#pragma unroll
    for (int kk = 0; kk < 8; ++kk){
      uint4 b0 = *(const uint4*)&pA[2*kk + hl][32*(2*wn+0) + l31][0];
      uint4 b1 = *(const uint4*)&pA[2*kk + hl][32*(2*wn+1) + l31][0];
      acc[0][0] = MFMA(wG[0][kk], b0, acc[0][0]);
      acc[0][1] = MFMA(wG[0][kk], b1, acc[0][1]);
      acc[1][0] = MFMA(wG[1][kk], b0, acc[1][0]);
      acc[1][1] = MFMA(wG[1][kk], b1, acc[1][1]);
    }
    // ---- relu -> HE panel ----
#pragma unroll
    for (int a = 0; a < 2; ++a)
#pragma unroll
      for (int bb = 0; bb < 2; ++bb)
#pragma unroll
        for (int q = 0; q < 4; ++q){
          uint2 o;
          o.x = pk2(fmaxf(acc[a][bb][4*q+0],0.f), fmaxf(acc[a][bb][4*q+1],0.f));
          o.y = pk2(fmaxf(acc[a][bb][4*q+2],0.f), fmaxf(acc[a][bb][4*q+3],0.f));
          *(uint2*)&pB[8*wm + 4*a + q][32*(2*wn+bb) + l31][4*hl] = o;
        }
    __syncthreads();

    // ---- v prefetch ----
    float vv[2][2];
#pragma unroll
    for (int a = 0; a < 2; ++a)
#pragma unroll
      for (int bb = 0; bb < 2; ++bb)
        vv[a][bb] = b2f((uint32_t)v_ws[(size_t)(b*32 + 4*cc + 2*wm + a)*128 + 64*wn + 32*bb + l31]);

    // ---- GEMM2: each A-read feeds 2 MFMAs ----
#pragma unroll
    for (int a = 0; a < 2; ++a)
#pragma unroll
      for (int bb = 0; bb < 2; ++bb)
#pragma unroll
        for (int r = 0; r < 16; ++r) acc[a][bb][r] = 0.f;
#pragma unroll
    for (int kk = 0; kk < 8; ++kk){
      uint4 a0 = *(const uint4*)&pB[2*kk + hl][32*(2*wm+0) + l31][0];
      uint4 a1 = *(const uint4*)&pB[2*kk + hl][32*(2*wm+1) + l31][0];
      acc[0][0] = MFMA(a0, wE[0][kk], acc[0][0]);
      acc[0][1] = MFMA(a0, wE[1][kk], acc[0][1]);
      acc[1][0] = MFMA(a1, wE[0][kk], acc[1][0]);
      acc[1][1] = MFMA(a1, wE[1][kk], acc[1][1]);
    }

    // ---- softmax over j per (i,d) via exp2; diag row r = rt+4g, rt = 2wm+a, g = cc>>1, hls = cc&1 ----
    const int g = cc >> 1, hls = cc & 1;
#pragma unroll
    for (int a = 0; a < 2; ++a){
#pragma unroll
      for (int bb = 0; bb < 2; ++bb){
#pragma unroll
        for (int r = 0; r < 16; ++r) acc[a][bb][r] = __builtin_amdgcn_exp2f(acc[a][bb][r]);
        float s = ((acc[a][bb][0]+acc[a][bb][1]) + (acc[a][bb][2]+acc[a][bb][3]))
                + ((acc[a][bb][4]+acc[a][bb][5]) + (acc[a][bb][6]+acc[a][bb][7]))
                + ((acc[a][bb][8]+acc[a][bb][9]) + (acc[a][bb][10]+acc[a][bb][11]))
                + ((acc[a][bb][12]+acc[a][bb][13]) + (acc[a][bb][14]+acc[a][bb][15]));
        s += __shfl_xor(s, 32);
        float c0v = wm ? acc[a][bb][2+a+0]  : acc[a][bb][a+0];
        float c1v = wm ? acc[a][bb][2+a+4]  : acc[a][bb][a+4];
        float c2v = wm ? acc[a][bb][2+a+8]  : acc[a][bb][a+8];
        float c3v = wm ? acc[a][bb][2+a+12] : acc[a][bb][a+12];
        float num = (g == 0) ? c0v : (g == 1) ? c1v : (g == 2) ? c2v : c3v;
        if (hl == hls){
          const int i = 4*cc + 2*wm + a;
          out[(size_t)(b*32 + i)*192 + 64*wn + 32*bb + l31] = num * __builtin_amdgcn_rcpf(s) * vv[a][bb];
        }
      }
    }

    if (cc < 7) hdgen(cc + 1);
    __syncthreads();
  }
}

// ---------------- launch ----------------
static constexpr size_t OFF_AEP = 0;
static constexpr size_t OFF_BEP = 32768;
static constexpr size_t OFF_GTP = 65536;
static constexpr size_t OFF_E2P = 98304;
static constexpr size_t OFF_O1T = 131072;
static constexpr size_t OFF_O2P = 147456;
static constexpr size_t OFF_C0  = 180224;
static constexpr size_t OFF_D1P = 180736;
static constexpr size_t OFF_QE  = 184832;
static constexpr size_t OFF_KE  = OFF_QE + (size_t)32768*128*2;
static constexpr size_t OFF_V   = OFF_KE + (size_t)32768*128*2;

extern "C" void kernel_launch(void* const* d_in, const int* in_sizes, int n_in,
                              void* d_out, int out_size, void* d_ws, size_t ws_size,
                              hipStream_t stream)
{
  (void)in_sizes; (void)n_in; (void)out_size; (void)ws_size;
  const float* pv   = (const float*)d_in[0];
  const float* feat = (const float*)d_in[1];
  const float* A1 = (const float*)d_in[2];  const float* ab1 = (const float*)d_in[3];
  const float* A2 = (const float*)d_in[4];  const float* ab2 = (const float*)d_in[5];
  const float* B1 = (const float*)d_in[6];  const float* bb1 = (const float*)d_in[7];
  const float* B2 = (const float*)d_in[8];  const float* bb2 = (const float*)d_in[9];
  const float* D1 = (const float*)d_in[10]; const float* db1 = (const float*)d_in[11];
  const float* D2 = (const float*)d_in[12]; const float* db2 = (const float*)d_in[13];
  const float* E1 = (const float*)d_in[14]; const float* eb1 = (const float*)d_in[15];
  const float* E2 = (const float*)d_in[16]; /* d_in[17] = eb2 unused (softmax-invariant) */
  const float* O1 = (const float*)d_in[18]; const float* ob1 = (const float*)d_in[19];
  const float* O2 = (const float*)d_in[20]; const float* ob2 = (const float*)d_in[21];

  char* ws = (char*)d_ws;
  ushort* aep = (ushort*)(ws + OFF_AEP);
  ushort* bep = (ushort*)(ws + OFF_BEP);
  ushort* gtp = (ushort*)(ws + OFF_GTP);
  ushort* e2p = (ushort*)(ws + OFF_E2P);
  ushort* o1t = (ushort*)(ws + OFF_O1T);
  ushort* o2p = (ushort*)(ws + OFF_O2P);
  float*  c0  = (float*)(ws + OFF_C0);
  ushort* d1p = (ushort*)(ws + OFF_D1P);
  ushort* qe  = (ushort*)(ws + OFF_QE);
  ushort* ke  = (ushort*)(ws + OFF_KE);
  ushort* vv  = (ushort*)(ws + OFF_V);
  float* out = (float*)d_out;

  hipLaunchKernelGGL(k_pre, dim3(361), dim3(256), 0, stream,
                     A2, B2, D2, E1, E2, O1, O2, ab2, bb2, db2, eb1, D1, db1,
                     aep, bep, gtp, e2p, o2p, o1t, d1p, c0);
  hipLaunchKernelGGL(k_point, dim3(512), dim3(256), 0, stream,
                     pv, feat, A1, ab1, B1, bb1, ob1, ob2, c0,
                     (const uint4*)aep, (const uint4*)bep, (const uint4*)o1t, (const uint4*)o2p,
                     qe, ke, vv, out);
  hipLaunchKernelGGL(k_main, dim3(1024), dim3(256), 0, stream,
                     pv, qe, ke, vv, (const uint4*)gtp, (const uint4*)e2p, (const uint4*)d1p,
                     out);
}

// Round 7
// 120.064 us; speedup vs baseline: 1.0464x; 1.0464x over previous
//
#include <hip/hip_runtime.h>
#include <hip/hip_bf16.h>
#include <cstdint>
#include <cstddef>

// PointAttention: out = concat( diag_softmax(eps_mlp((q_i - k_j + pij)*s)) * v , features )
// Folding: AE=s*A2@E1, BE=s*B2@E1, G=s*D2@E1, c0=s*(ab2-bb2+db2)@E1+eb1 (folded into qe); eb2 drops out.
// Softmax: logits O(1) -> no max-sub; E2 panel pre-scaled by log2e -> exp2.
// k_main v3: barrier-free all-register dataflow. Wave owns 2 i-chunks end-to-end; HD->GEMM1 and
// GEMM1->GEMM2 handoffs via cvt_pk_bf16 + permlane32_swap (no LDS transpose, no inner barriers).
// Weights (G^T, E2) stream from LDS (shared read-only panels); each b128 read feeds 2 MFMAs.

#define SCALE 0.08838834764831843f
#define LOG2E 1.4426950408889634f

typedef __bf16 bf16x8 __attribute__((ext_vector_type(8)));
typedef float f32x16 __attribute__((ext_vector_type(16)));
typedef unsigned int u32x2 __attribute__((ext_vector_type(2)));

__device__ __forceinline__ ushort f2b(float f){
  __hip_bfloat16 h = __float2bfloat16(f);
  return __builtin_bit_cast(ushort, h);
}
__device__ __forceinline__ float b2f(uint32_t s){
  union { uint32_t u; float f; } x; x.u = s << 16; return x.f;
}
__device__ __forceinline__ float blo(uint32_t u){
  union { uint32_t x; float f; } v; v.x = u << 16; return v.f;
}
__device__ __forceinline__ float bhi(uint32_t u){
  union { uint32_t x; float f; } v; v.x = u & 0xffff0000u; return v.f;
}
__device__ __forceinline__ uint32_t pk2(float a, float b){
  union { __hip_bfloat162 h2; uint32_t u; } x;
  x.h2.x = __float2bfloat16(a); x.h2.y = __float2bfloat16(b);
  return x.u;
}
__device__ __forceinline__ f32x16 MFMA(uint4 a, uint4 b, f32x16 c){
  return __builtin_amdgcn_mfma_f32_32x32x16_bf16(
      __builtin_bit_cast(bf16x8, a), __builtin_bit_cast(bf16x8, b), c, 0, 0, 0);
}

// permlane32_swap(a,b) -> (x = [a.lo | b.lo], y = [a.hi | b.hi]) per half-wave.
__device__ __forceinline__ uint2 pswap(uint32_t a, uint32_t b){
#if __has_builtin(__builtin_amdgcn_permlane32_swap)
  u32x2 r = __builtin_amdgcn_permlane32_swap(a, b, false, false);
  uint2 o; o.x = r[0]; o.y = r[1]; return o;
#else
  uint32_t am = (uint32_t)__shfl_xor((int)a, 32);
  uint32_t bm = (uint32_t)__shfl_xor((int)b, 32);
  bool hi = (threadIdx.x & 32) != 0;
  uint2 o; o.x = hi ? bm : a; o.y = hi ? b : am; return o;
#endif
}

// Pack a 32x32 f32 C-tile (col=l31, row=(r&3)+4*hl+8*(r>>2)) into two bf16 MFMA operand
// fragments (lane=col, k=8*hl+e over rows 0..15 / 16..31), with relu.
__device__ __forceinline__ void packswap(const f32x16 c, uint4& f0, uint4& f1){
  uint32_t p01 = pk2(fmaxf(c[0],0.f),  fmaxf(c[1],0.f));
  uint32_t p23 = pk2(fmaxf(c[2],0.f),  fmaxf(c[3],0.f));
  uint32_t p45 = pk2(fmaxf(c[4],0.f),  fmaxf(c[5],0.f));
  uint32_t p67 = pk2(fmaxf(c[6],0.f),  fmaxf(c[7],0.f));
  uint32_t p89 = pk2(fmaxf(c[8],0.f),  fmaxf(c[9],0.f));
  uint32_t pab = pk2(fmaxf(c[10],0.f), fmaxf(c[11],0.f));
  uint32_t pcd = pk2(fmaxf(c[12],0.f), fmaxf(c[13],0.f));
  uint32_t pef = pk2(fmaxf(c[14],0.f), fmaxf(c[15],0.f));
  uint2 s0 = pswap(p01, p45), s1 = pswap(p23, p67);
  uint2 s2 = pswap(p89, pcd), s3 = pswap(pab, pef);
  f0.x = s0.x; f0.y = s1.x; f0.z = s0.y; f0.w = s1.y;
  f1.x = s2.x; f1.y = s3.x; f1.z = s2.y; f1.w = s3.y;
}

// ---------------- Kernel P: weight folding + panelization ----------------
// panel[k_oct][x][e] = Mat[8*k_oct+e][x]  (bf16, conflict-free for frag ds_read_b128)
__global__ __launch_bounds__(256) void k_pre(
    const float* __restrict__ A2, const float* __restrict__ B2, const float* __restrict__ D2,
    const float* __restrict__ E1, const float* __restrict__ E2,
    const float* __restrict__ O1, const float* __restrict__ O2,
    const float* __restrict__ ab2, const float* __restrict__ bb2, const float* __restrict__ db2,
    const float* __restrict__ eb1,
    const float* __restrict__ D1, const float* __restrict__ db1,
    ushort* __restrict__ aep, ushort* __restrict__ bep, ushort* __restrict__ gtp,
    ushort* __restrict__ e2p, ushort* __restrict__ o2p, ushort* __restrict__ o1t,
    ushort* __restrict__ d1p, float* __restrict__ c0)
{
  const int bid = blockIdx.x, tid = threadIdx.x;
  if (bid < 192){                 // AE / BE / G = s*(W @ E1), panelized
    const float* W = (bid < 64) ? A2 : (bid < 128) ? B2 : D2;
    ushort* dst    = (bid < 64) ? aep : (bid < 128) ? bep : gtp;
    int flat = (bid & 63)*256 + tid;
    int co = flat >> 10, rem = flat & 1023, h = rem >> 3, i = rem & 7;
    int r = co*8 + i;
    float acc = 0.f;
    for (int t = 0; t < 128; ++t) acc = fmaf(W[r*128 + t], E1[t*128 + h], acc);
    dst[(co*128 + h)*8 + i] = f2b(acc * SCALE);
  } else if (bid < 256){          // E2 panel, pre-scaled by log2e (softmax via exp2)
    int flat = (bid - 192)*256 + tid;
    int co = flat >> 10, rem = flat & 1023, d = rem >> 3, i = rem & 7;
    e2p[(co*128 + d)*8 + i] = f2b(E2[(co*8 + i)*128 + d] * LOG2E);
  } else if (bid < 320){          // O2 panel
    int flat = (bid - 256)*256 + tid;
    int co = flat >> 10, rem = flat & 1023, d = rem >> 3, i = rem & 7;
    o2p[(co*128 + d)*8 + i] = f2b(O2[(co*8 + i)*128 + d]);
  } else if (bid < 352){          // O1^T panel (A-operand: rows=o, k=f)
    int flat = (bid - 320)*256 + tid;   // 8192 elems
    int fo = flat >> 10, rem = flat & 1023, o = rem >> 3, e = rem & 7;
    o1t[(fo*128 + o)*8 + e] = f2b(O1[(fo*8 + e)*128 + o]);
  } else if (bid < 360){          // D1 A-frag panel: [2 koct][128 cd][8]
    int flat = (bid - 352)*256 + tid;   // 2048 elems
    int koct = flat >> 10, cd = (flat >> 3) & 127, e = flat & 7;
    float val = 0.f;
    if (koct == 0){
      if (e < 3) val = D1[e*128 + cd];
      else if (e == 3) val = db1[cd];
    }
    d1p[flat] = f2b(val);
  } else {
    if (tid < 128){
      float acc = 0.f;
      for (int t = 0; t < 128; ++t) acc = fmaf(ab2[t] - bb2[t] + db2[t], E1[t*128 + tid], acc);
      c0[tid] = acc * SCALE + eb1[tid];
    }
  }
}

// ---------------- Kernel Q: per-point qe/ke/v + features passthrough ----------------
__device__ __forceinline__ void gemm64x128(const ushort (*sa)[64][8], const ushort (*sw)[128][8],
                                           int w, int l31, int hl, int p0,
                                           const float* __restrict__ bias,
                                           ushort* __restrict__ dst)
{
  const int rw = w >> 1, ctb = (w & 1) * 2;
  f32x16 acc0, acc1;
#pragma unroll
  for (int r = 0; r < 16; ++r){ acc0[r] = 0.f; acc1[r] = 0.f; }
#pragma unroll
  for (int kk = 0; kk < 8; ++kk){
    uint4 a  = *(const uint4*)&sa[2*kk + hl][32*rw + l31][0];
    uint4 b0 = *(const uint4*)&sw[2*kk + hl][32*ctb + l31][0];
    uint4 b1 = *(const uint4*)&sw[2*kk + hl][32*(ctb+1) + l31][0];
    acc0 = MFMA(a, b0, acc0);
    acc1 = MFMA(a, b1, acc1);
  }
#pragma unroll
  for (int t = 0; t < 2; ++t){
    const f32x16 acc = t ? acc1 : acc0;
    const int d = 32*(ctb + t) + l31;
    const float bv = bias ? bias[d] : 0.f;
#pragma unroll
    for (int r = 0; r < 16; ++r){
      int row = 32*rw + (r & 3) + 8*(r >> 2) + 4*hl;
      dst[(size_t)(p0 + row)*128 + d] = f2b(acc[r] + bv);
    }
  }
}

__global__ __launch_bounds__(256, 2) void k_point(
    const float* __restrict__ pv, const float* __restrict__ feat,
    const float* __restrict__ A1, const float* __restrict__ ab1,
    const float* __restrict__ B1, const float* __restrict__ bb1,
    const float* __restrict__ ob1, const float* __restrict__ ob2,
    const float* __restrict__ c0,
    const uint4* __restrict__ aep, const uint4* __restrict__ bep,
    const uint4* __restrict__ o1t, const uint4* __restrict__ o2p,
    ushort* __restrict__ qe_ws, ushort* __restrict__ ke_ws, ushort* __restrict__ v_ws,
    float* __restrict__ out)
{
  __shared__ ushort sW[16][128][8];   // 32 KB weight panel
  __shared__ ushort sA[16][64][8];    // 16 KB activation panel
  __shared__ ushort sF[8][64][8];     // 8 KB  feature panel
  __shared__ float  sLw[3][128];
  __shared__ float  sLb[128];
  __shared__ float  sLb2[128];

  const int tid = threadIdx.x;
  const int p0  = blockIdx.x * 64;
  const int w = tid >> 6, lane = tid & 63, l31 = lane & 31, hl = lane >> 5;

  // exact f32 features passthrough: out[:,:,128:192]
  for (int idx = tid; idx < 64*16; idx += 256){
    int p = idx >> 4, k4 = idx & 15;
    float4 f = ((const float4*)(feat + (size_t)(p0 + p)*64))[k4];
    ((float4*)(out + (size_t)(p0 + p)*192 + 128))[k4] = f;
  }

  // ---- phase A: ha = relu(xyz@A1+ab1); qe = ha@AE + c0 ----
  for (int idx = tid; idx < 2048; idx += 256) ((uint4*)sW)[idx] = aep[idx];
  for (int idx = tid; idx < 384; idx += 256) ((float*)sLw)[idx] = A1[idx];
  if (tid < 128) sLb[tid] = ab1[tid];
  __syncthreads();
  {
    int p = tid & 63, ob = tid >> 6;
    float x0 = pv[(size_t)(p0+p)*3+0], x1 = pv[(size_t)(p0+p)*3+1], x2 = pv[(size_t)(p0+p)*3+2];
#pragma unroll
    for (int it = 0; it < 4; ++it){
      int oct = ob + 4*it;
      float h[8];
#pragma unroll
      for (int e = 0; e < 8; ++e){
        int cd = oct*8 + e;
        float t = fmaf(x0, sLw[0][cd], fmaf(x1, sLw[1][cd], fmaf(x2, sLw[2][cd], sLb[cd])));
        h[e] = fmaxf(t, 0.f);
      }
      uint4 u; u.x = pk2(h[0],h[1]); u.y = pk2(h[2],h[3]); u.z = pk2(h[4],h[5]); u.w = pk2(h[6],h[7]);
      *(uint4*)&sA[oct][p][0] = u;
    }
  }
  __syncthreads();
  gemm64x128(sA, sW, w, l31, hl, p0, c0, qe_ws);
  __syncthreads();

  // ---- phase B: ke = hb@BE ----
  for (int idx = tid; idx < 2048; idx += 256) ((uint4*)sW)[idx] = bep[idx];
  for (int idx = tid; idx < 384; idx += 256) ((float*)sLw)[idx] = B1[idx];
  if (tid < 128) sLb[tid] = bb1[tid];
  __syncthreads();
  {
    int p = tid & 63, ob = tid >> 6;
    float x0 = pv[(size_t)(p0+p)*3+0], x1 = pv[(size_t)(p0+p)*3+1], x2 = pv[(size_t)(p0+p)*3+2];
#pragma unroll
    for (int it = 0; it < 4; ++it){
      int oct = ob + 4*it;
      float h[8];
#pragma unroll
      for (int e = 0; e < 8; ++e){
        int cd = oct*8 + e;
        float t = fmaf(x0, sLw[0][cd], fmaf(x1, sLw[1][cd], fmaf(x2, sLw[2][cd], sLb[cd])));
        h[e] = fmaxf(t, 0.f);
      }
      uint4 u; u.x = pk2(h[0],h[1]); u.y = pk2(h[2],h[3]); u.z = pk2(h[4],h[5]); u.w = pk2(h[6],h[7]);
      *(uint4*)&sA[oct][p][0] = u;
    }
  }
  __syncthreads();
  gemm64x128(sA, sW, w, l31, hl, p0, nullptr, ke_ws);
  __syncthreads();

  // ---- phase C: ho^T = relu(O1^T @ feat^T + ob1) ----
  for (int idx = tid; idx < 512; idx += 256){
    int p = idx & 63, fo = idx >> 6;
    const float* fp = feat + (size_t)(p0 + p)*64 + 8*fo;
    float4 f0 = ((const float4*)fp)[0], f1 = ((const float4*)fp)[1];
    uint4 u; u.x = pk2(f0.x,f0.y); u.y = pk2(f0.z,f0.w); u.z = pk2(f1.x,f1.y); u.w = pk2(f1.z,f1.w);
    *(uint4*)&sF[fo][p][0] = u;
  }
  for (int idx = tid; idx < 1024; idx += 256) ((uint4*)sW)[idx] = o1t[idx];
  if (tid < 128) sLb[tid] = ob1[tid];
  __syncthreads();
  {
    f32x16 acc0, acc1;
#pragma unroll
    for (int r = 0; r < 16; ++r){ acc0[r] = 0.f; acc1[r] = 0.f; }
#pragma unroll
    for (int kk = 0; kk < 4; ++kk){
      uint4 a  = *(const uint4*)&sW[2*kk + hl][32*w + l31][0];
      uint4 b0 = *(const uint4*)&sF[2*kk + hl][l31][0];
      uint4 b1 = *(const uint4*)&sF[2*kk + hl][32 + l31][0];
      acc0 = MFMA(a, b0, acc0);
      acc1 = MFMA(a, b1, acc1);
    }
#pragma unroll
    for (int t = 0; t < 2; ++t){
      const f32x16 acc = t ? acc1 : acc0;
      const int pt = 32*t + l31;
#pragma unroll
      for (int q = 0; q < 4; ++q){
        int o0 = 32*w + 8*q + 4*hl;
        float z0 = fmaxf(acc[4*q+0] + sLb[o0+0], 0.f);
        float z1 = fmaxf(acc[4*q+1] + sLb[o0+1], 0.f);
        float z2 = fmaxf(acc[4*q+2] + sLb[o0+2], 0.f);
        float z3 = fmaxf(acc[4*q+3] + sLb[o0+3], 0.f);
        uint2 u; u.x = pk2(z0, z1); u.y = pk2(z2, z3);
        *(uint2*)&sA[4*w + q][pt][4*hl] = u;
      }
    }
  }
  __syncthreads();

  // ---- phase D: v = ho @ O2 + ob2 ----
  for (int idx = tid; idx < 2048; idx += 256) ((uint4*)sW)[idx] = o2p[idx];
  if (tid < 128) sLb2[tid] = ob2[tid];
  __syncthreads();
  {
    const int rw = w >> 1, ctb = (w & 1) * 2;
    f32x16 acc0, acc1;
#pragma unroll
    for (int r = 0; r < 16; ++r){ acc0[r] = 0.f; acc1[r] = 0.f; }
#pragma unroll
    for (int kk = 0; kk < 8; ++kk){
      uint4 a  = *(const uint4*)&sA[2*kk + hl][32*rw + l31][0];
      uint4 b0 = *(const uint4*)&sW[2*kk + hl][32*ctb + l31][0];
      uint4 b1 = *(const uint4*)&sW[2*kk + hl][32*(ctb+1) + l31][0];
      acc0 = MFMA(a, b0, acc0);
      acc1 = MFMA(a, b1, acc1);
    }
#pragma unroll
    for (int t = 0; t < 2; ++t){
      const f32x16 acc = t ? acc1 : acc0;
      const int d = 32*(ctb + t) + l31;
      const float bias = sLb2[d];
#pragma unroll
      for (int r = 0; r < 16; ++r){
        int row = 32*rw + (r & 3) + 8*(r >> 2) + 4*hl;
        v_ws[(size_t)(p0 + row)*128 + d] = f2b(acc[r] + bias);
      }
    }
  }
}

// ---------------- Kernel M: barrier-free per-voxel attention core ----------------
// One voxel per block, 4 waves; wave w owns rows i in {8w..8w+7}, processed as 4 pairs.
// All activation dataflow in registers (permlane32_swap transposes); weights stream from LDS.
__global__ __launch_bounds__(256, 2) void k_main(
    const float* __restrict__ pv,
    const ushort* __restrict__ qe_ws, const ushort* __restrict__ ke_ws, const ushort* __restrict__ v_ws,
    const uint4* __restrict__ gtp, const uint4* __restrict__ e2p, const uint4* __restrict__ d1p,
    float* __restrict__ out)
{
  __shared__ uint4 sG[2048];      // 32 KB: G^T panel
  __shared__ uint4 sE[2048];      // 32 KB: E2*log2e panel
  __shared__ uint2 sK[1024];      // 8 KB: ke transposed pair layout [slot16][hl2][j32]
  __shared__ float sXYZ[32][3];   // 384 B

  const int tid = threadIdx.x;
  const int b = blockIdx.x;
  const int w = tid >> 6, lane = tid & 63, l31 = lane & 31, hl = lane >> 5;

  for (int idx = tid; idx < 2048; idx += 256){ sG[idx] = gtp[idx]; sE[idx] = e2p[idx]; }
  for (int idx = tid; idx < 1024; idx += 256){
    int j = idx & 31, rest = idx >> 5;
    int khl = rest & 1, slot = rest >> 1;
    int h0 = 32*(slot >> 2) + 8*(slot & 3) + 4*khl;
    sK[idx] = *(const uint2*)(ke_ws + (size_t)(b*32 + j)*128 + h0);
  }
  for (int idx = tid; idx < 96; idx += 256) ((float*)sXYZ)[idx] = pv[(size_t)b*96 + idx];

  uint4 wD[4];
#pragma unroll
  for (int t = 0; t < 4; ++t) wD[t] = d1p[hl*128 + 32*t + l31];
  f32x16 ZERO;
#pragma unroll
  for (int r = 0; r < 16; ++r) ZERO[r] = 0.f;
  __syncthreads();

  const float xj0 = sXYZ[l31][0], xj1 = sXYZ[l31][1], xj2 = sXYZ[l31][2];
  const ushort* qbase = qe_ws + (size_t)b*32*128;

#pragma unroll
  for (int pp = 0; pp < 4; ++pp){
    const int i0 = 8*w + 2*pp, i1 = i0 + 1;

    // ---- distance B-fragments (K=4: dx,dy,dz,1; upper octet zero vs zero A) ----
    uint4 bDa, bDb;
    {
      float a0 = sXYZ[i0][0], a1 = sXYZ[i0][1], a2 = sXYZ[i0][2];
      float c0_ = sXYZ[i1][0], c1_ = sXYZ[i1][1], c2_ = sXYZ[i1][2];
      bDa.x = pk2(fabsf(a0-xj0), fabsf(a1-xj1)); bDa.y = pk2(fabsf(a2-xj2), 1.0f);
      bDa.z = 0u; bDa.w = 0u;
      bDb.x = pk2(fabsf(c0_-xj0), fabsf(c1_-xj1)); bDb.y = pk2(fabsf(c2_-xj2), 1.0f);
      bDb.z = 0u; bDb.w = 0u;
    }

    // ---- HD = relu(|dxyz| @ [D1;db1]) -> register B-fragments (8 per chunk) ----
    uint4 hdA[8], hdB[8];
#pragma unroll
    for (int t = 0; t < 4; ++t){
      f32x16 ca = MFMA(wD[t], bDa, ZERO);
      f32x16 cb = MFMA(wD[t], bDb, ZERO);
      packswap(ca, hdA[2*t], hdA[2*t+1]);
      packswap(cb, hdB[2*t], hdB[2*t+1]);
    }

    // ---- GEMM1 per h-tile: HE^T = relu(G^T@HD^T + qe_i - ke_j) -> A-fragments ----
    uint4 heA[8], heB[8];
#pragma unroll
    for (int t = 0; t < 4; ++t){
      f32x16 aA, aB;
#pragma unroll
      for (int q = 0; q < 4; ++q){
        uint2 kq = sK[((t*4 + q)*2 + hl)*32 + l31];
        uint2 qa = *(const uint2*)(qbase + (size_t)i0*128 + 32*t + 8*q + 4*hl);
        uint2 qb = *(const uint2*)(qbase + (size_t)i1*128 + 32*t + 8*q + 4*hl);
        float k0 = blo(kq.x), k1 = bhi(kq.x), k2 = blo(kq.y), k3 = bhi(kq.y);
        aA[4*q+0] = blo(qa.x) - k0; aA[4*q+1] = bhi(qa.x) - k1;
        aA[4*q+2] = blo(qa.y) - k2; aA[4*q+3] = bhi(qa.y) - k3;
        aB[4*q+0] = blo(qb.x) - k0; aB[4*q+1] = bhi(qb.x) - k1;
        aB[4*q+2] = blo(qb.y) - k2; aB[4*q+3] = bhi(qb.y) - k3;
      }
#pragma unroll
      for (int kk = 0; kk < 8; ++kk){
        uint4 wg = sG[(2*kk + hl)*128 + 32*t + l31];   // shared read feeds 2 MFMAs
        aA = MFMA(wg, hdA[kk], aA);
        aB = MFMA(wg, hdB[kk], aB);
      }
      packswap(aA, heA[2*t], heA[2*t+1]);
      packswap(aB, heB[2*t], heB[2*t+1]);
    }

    // ---- GEMM2 per d-tile + diagonal softmax ----
    const int rl   = (2*pp) & 3;   // i0&3 (static); i1&3 = rl+1
    const int hsel = pp >> 1;      // (i>>2)&1, same for i0,i1 (static)
#pragma unroll
    for (int t = 0; t < 4; ++t){
      float va = b2f((uint32_t)v_ws[(size_t)(b*32 + i0)*128 + 32*t + l31]);
      float vb = b2f((uint32_t)v_ws[(size_t)(b*32 + i1)*128 + 32*t + l31]);
      f32x16 cA, cB;
#pragma unroll
      for (int kk = 0; kk < 8; ++kk){
        uint4 we = sE[(2*kk + hl)*128 + 32*t + l31];   // shared read feeds 2 MFMAs
        cA = MFMA(heA[kk], we, kk ? cA : ZERO);
        cB = MFMA(heB[kk], we, kk ? cB : ZERO);
      }
#pragma unroll
      for (int r = 0; r < 16; ++r) cA[r] = __builtin_amdgcn_exp2f(cA[r]);
#pragma unroll
      for (int r = 0; r < 16; ++r) cB[r] = __builtin_amdgcn_exp2f(cB[r]);
      float sA = ((cA[0]+cA[1])+(cA[2]+cA[3])) + ((cA[4]+cA[5])+(cA[6]+cA[7]))
               + ((cA[8]+cA[9])+(cA[10]+cA[11])) + ((cA[12]+cA[13])+(cA[14]+cA[15]));
      float sB = ((cB[0]+cB[1])+(cB[2]+cB[3])) + ((cB[4]+cB[5])+(cB[6]+cB[7]))
               + ((cB[8]+cB[9])+(cB[10]+cB[11])) + ((cB[12]+cB[13])+(cB[14]+cB[15]));
      uint2 swA = pswap(__builtin_bit_cast(uint32_t, sA), __builtin_bit_cast(uint32_t, sA));
      uint2 swB = pswap(__builtin_bit_cast(uint32_t, sB), __builtin_bit_cast(uint32_t, sB));
      float sAt = __builtin_bit_cast(float, swA.x) + __builtin_bit_cast(float, swA.y);
      float sBt = __builtin_bit_cast(float, swB.x) + __builtin_bit_cast(float, swB.y);
      float nA = (w == 0) ? cA[rl]   : (w == 1) ? cA[rl+4]   : (w == 2) ? cA[rl+8]   : cA[rl+12];
      float nB = (w == 0) ? cB[rl+1] : (w == 1) ? cB[rl+5]   : (w == 2) ? cB[rl+9]   : cB[rl+13];
      if (hl == hsel){
        out[(size_t)(b*32 + i0)*192 + 32*t + l31] = nA * __builtin_amdgcn_rcpf(sAt) * va;
        out[(size_t)(b*32 + i1)*192 + 32*t + l31] = nB * __builtin_amdgcn_rcpf(sBt) * vb;
      }
    }
  }
}

// ---------------- launch ----------------
static constexpr size_t OFF_AEP = 0;
static constexpr size_t OFF_BEP = 32768;
static constexpr size_t OFF_GTP = 65536;
static constexpr size_t OFF_E2P = 98304;
static constexpr size_t OFF_O1T = 131072;
static constexpr size_t OFF_O2P = 147456;
static constexpr size_t OFF_C0  = 180224;
static constexpr size_t OFF_D1P = 180736;
static constexpr size_t OFF_QE  = 184832;
static constexpr size_t OFF_KE  = OFF_QE + (size_t)32768*128*2;
static constexpr size_t OFF_V   = OFF_KE + (size_t)32768*128*2;

extern "C" void kernel_launch(void* const* d_in, const int* in_sizes, int n_in,
                              void* d_out, int out_size, void* d_ws, size_t ws_size,
                              hipStream_t stream)
{
  (void)in_sizes; (void)n_in; (void)out_size; (void)ws_size;
  const float* pv   = (const float*)d_in[0];
  const float* feat = (const float*)d_in[1];
  const float* A1 = (const float*)d_in[2];  const float* ab1 = (const float*)d_in[3];
  const float* A2 = (const float*)d_in[4];  const float* ab2 = (const float*)d_in[5];
  const float* B1 = (const float*)d_in[6];  const float* bb1 = (const float*)d_in[7];
  const float* B2 = (const float*)d_in[8];  const float* bb2 = (const float*)d_in[9];
  const float* D1 = (const float*)d_in[10]; const float* db1 = (const float*)d_in[11];
  const float* D2 = (const float*)d_in[12]; const float* db2 = (const float*)d_in[13];
  const float* E1 = (const float*)d_in[14]; const float* eb1 = (const float*)d_in[15];
  const float* E2 = (const float*)d_in[16]; /* d_in[17] = eb2 unused (softmax-invariant) */
  const float* O1 = (const float*)d_in[18]; const float* ob1 = (const float*)d_in[19];
  const float* O2 = (const float*)d_in[20]; const float* ob2 = (const float*)d_in[21];

  char* ws = (char*)d_ws;
  ushort* aep = (ushort*)(ws + OFF_AEP);
  ushort* bep = (ushort*)(ws + OFF_BEP);
  ushort* gtp = (ushort*)(ws + OFF_GTP);
  ushort* e2p = (ushort*)(ws + OFF_E2P);
  ushort* o1t = (ushort*)(ws + OFF_O1T);
  ushort* o2p = (ushort*)(ws + OFF_O2P);
  float*  c0  = (float*)(ws + OFF_C0);
  ushort* d1p = (ushort*)(ws + OFF_D1P);
  ushort* qe  = (ushort*)(ws + OFF_QE);
  ushort* ke  = (ushort*)(ws + OFF_KE);
  ushort* vv  = (ushort*)(ws + OFF_V);
  float* out = (float*)d_out;

  hipLaunchKernelGGL(k_pre, dim3(361), dim3(256), 0, stream,
                     A2, B2, D2, E1, E2, O1, O2, ab2, bb2, db2, eb1, D1, db1,
                     aep, bep, gtp, e2p, o2p, o1t, d1p, c0);
  hipLaunchKernelGGL(k_point, dim3(512), dim3(256), 0, stream,
                     pv, feat, A1, ab1, B1, bb1, ob1, ob2, c0,
                     (const uint4*)aep, (const uint4*)bep, (const uint4*)o1t, (const uint4*)o2p,
                     qe, ke, vv, out);
  hipLaunchKernelGGL(k_main, dim3(1024), dim3(256), 0, stream,
                     pv, qe, ke, vv, (const uint4*)gtp, (const uint4*)e2p, (const uint4*)d1p,
                     out);
}